// Round 12
// baseline (191.068 us; speedup 1.0000x reference)
//
#include <hip/hip_runtime.h>
#include <hip/hip_bf16.h>
#include <math.h>
#include <stdint.h>

// RandomProjectionQuantizer — bf16 MFMA filter + exact fp32 top-8 rescore.
//   mel [32,80,4000] f32, proj [2,80,64] f32, codebooks [2,1024,64] f32
//   codes[c,b,t] = argmax_k ( (mel[b,:,t] @ proj[c]) . cb[c,k,:]/||cb[c,k]|| )
//
// R12 = R11 (169us) with LDS 33.3K -> 25.1K for 6 blocks/CU (24 waves, 75%):
//   KT 64->32 (cbuf 2x4KB, R8-verified addressing; R8's regression was the
//   (256,5) VGPR-48 spill, not KT), candT[16][64][2]=8192B aliased into cbuf,
//   scv/sck[64][9] aliased too (extra barrier between cand-read & scv-write).
//   __launch_bounds__(256,6): VGPR cap 85 >> measured 64 -> no spill.
// Depth-2 staging prefetch kept (harmless). Filter math / swizzle / MFMA
// mapping / top-2 packing / top-8 merge / exact rescore: proven lineage.

#define B      32
#define NMELS  80
#define TSTEPS 4000
#define NCB    2
#define KCB    1024
#define DDIM   64
#define TPB    256
#define TM     64            // t's per block (16 per wave)
#define KT     32            // codebook rows per LDS tile (4 KB bf16)
#define NKT    (KCB / KT)    // 32 tiles
#define PPAD   66            // P row stride (floats) — proven

typedef short bf16x8 __attribute__((ext_vector_type(8)));
typedef float f32x4  __attribute__((ext_vector_type(4)));

#define WS_CB_OFF   8192                         // bytes: invn table first
#define WS_NEEDED   (8192 + NCB*KCB*DDIM*2)      // 270336 (proven fits, R4)

static __device__ __forceinline__ uint32_t bits(float f) {
    return __builtin_bit_cast(uint32_t, f);
}
static __device__ __forceinline__ float fbits(uint32_t u) {
    return __builtin_bit_cast(float, u);
}
// round-to-nearest-even f32 -> bf16 (returns low 16 bits)
static __device__ __forceinline__ uint32_t rne16(uint32_t u) {
    return (u + 0x7FFFu + ((u >> 16) & 1u)) >> 16;
}

// ---------------------------------------------------------------- prep ----
__global__ __launch_bounds__(TPB) void rpq_prep(const float* __restrict__ cb,
                                                float* __restrict__ ws)
{
    const int idx = blockIdx.x * TPB + threadIdx.x;
    if (idx >= NCB * KCB) return;

    const float4* row = (const float4*)(cb + (size_t)idx * DDIM);
    float4 v[16];
    float ss = 0.f;
    #pragma unroll
    for (int i = 0; i < 16; ++i) {
        v[i] = row[i];
        ss += v[i].x*v[i].x + v[i].y*v[i].y + v[i].z*v[i].z + v[i].w*v[i].w;
    }
    const float inv = 1.0f / fmaxf(sqrtf(ss), 1e-12f);
    ws[idx] = inv;

    uint32_t dw[32];
    #pragma unroll
    for (int i = 0; i < 16; ++i) {
        dw[2*i]   = rne16(bits(v[i].x * inv)) | (rne16(bits(v[i].y * inv)) << 16);
        dw[2*i+1] = rne16(bits(v[i].z * inv)) | (rne16(bits(v[i].w * inv)) << 16);
    }
    uint4* dst = (uint4*)((char*)ws + WS_CB_OFF + (size_t)idx * 128);
    #pragma unroll
    for (int i = 0; i < 8; ++i)
        dst[i] = make_uint4(dw[4*i], dw[4*i+1], dw[4*i+2], dw[4*i+3]);
}

// ---------------------------------------------------------------- main ----
__global__ __launch_bounds__(TPB, 6) void rpq_main(
    const float* __restrict__ mel,
    const float* __restrict__ proj,
    const float* __restrict__ cb,
    const float* __restrict__ ws,
    int* __restrict__ out)
{
    const int tid  = threadIdx.x;
    const int b    = blockIdx.y;
    const int c    = blockIdx.z;
    const int t0   = blockIdx.x * TM;

    const int l    = tid & 63;
    const int wid  = tid >> 6;      // wave 0..3
    const int lrow = l & 15;        // A/B row-col within 16x16
    const int lgrp = l >> 4;        // k-octet group 0..3

    // projS: phase-1 only. cbuf/PL written after S2. candT aliases cbuf
    // (written after filter's final barrier); scv/sck alias candT (written
    // after the S4b barrier that ends all candT reads).
    __shared__ union __align__(16) {
        float projS[NMELS * DDIM];              // 20480 B
        struct {
            union {
                char     cbuf[2][KT * 128];     // 8192 B (bf16 dbuf, swizzled)
                uint32_t candT[16][TM][2];      // 8192 B (transposed top-2)
                struct {
                    float scv[TM][9];           // 2304 B
                    int   sck[TM][9];           // 2304 B
                } m;
            } a;
            float PL[TM * PPAD];                // 16896 B
        } p2;
    } U;                                        // total 25088 B -> 6 blocks/CU

    const char*  wscb   = (const char*)ws + WS_CB_OFF + (size_t)c * (KCB * 128);
    const float* invn_g = ws + (size_t)c * KCB;

    // ---- stage proj[c] into LDS ----
    {
        const float4* src = (const float4*)(proj + (size_t)c * NMELS * DDIM);
        float4* dst = (float4*)U.projS;
        for (int i = tid; i < NMELS * DDIM / 4; i += TPB) dst[i] = src[i];
    }
    __syncthreads();                                  // S1

    // ---- DEPTH-2 prefetch: tiles 0 and 1 loaded before phase-1 ----
    const int srow = tid >> 3;     // staging row 0..31
    const int sq   = tid & 7;      // 16B slot in 128B row
    uint4 ga, gb;
    ga = *(const uint4*)(wscb + (size_t)tid * 16);                    // tile 0
    gb = *(const uint4*)(wscb + (size_t)KT * 128 + (size_t)tid * 16); // tile 1

    // ---- phase 1: P[t][d]; thread = (tq = tid&15 -> 4 t's, dg = tid>>4) ----
    {
        const int tq = tid & 15;
        const int dg = tid >> 4;
        const int tbase  = t0 + tq * 4;
        const int tb_c   = (tbase <= TSTEPS - 4) ? tbase : (TSTEPS - 4);
        const float* mp  = mel + (size_t)b * NMELS * TSTEPS + tb_c;

        float Pa[4][4];
        #pragma unroll
        for (int i = 0; i < 4; ++i)
            #pragma unroll
            for (int j = 0; j < 4; ++j) Pa[i][j] = 0.f;

        for (int n = 0; n < NMELS; ++n) {
            const float4 m4 = *(const float4*)(mp + (size_t)n * TSTEPS);
            const float4 w  = *(const float4*)&U.projS[n * DDIM + dg * 4];
            Pa[0][0] = fmaf(m4.x, w.x, Pa[0][0]); Pa[0][1] = fmaf(m4.x, w.y, Pa[0][1]);
            Pa[0][2] = fmaf(m4.x, w.z, Pa[0][2]); Pa[0][3] = fmaf(m4.x, w.w, Pa[0][3]);
            Pa[1][0] = fmaf(m4.y, w.x, Pa[1][0]); Pa[1][1] = fmaf(m4.y, w.y, Pa[1][1]);
            Pa[1][2] = fmaf(m4.y, w.z, Pa[1][2]); Pa[1][3] = fmaf(m4.y, w.w, Pa[1][3]);
            Pa[2][0] = fmaf(m4.z, w.x, Pa[2][0]); Pa[2][1] = fmaf(m4.z, w.y, Pa[2][1]);
            Pa[2][2] = fmaf(m4.z, w.z, Pa[2][2]); Pa[2][3] = fmaf(m4.z, w.w, Pa[2][3]);
            Pa[3][0] = fmaf(m4.w, w.x, Pa[3][0]); Pa[3][1] = fmaf(m4.w, w.y, Pa[3][1]);
            Pa[3][2] = fmaf(m4.w, w.z, Pa[3][2]); Pa[3][3] = fmaf(m4.w, w.w, Pa[3][3]);
        }
        __syncthreads();                              // S2: projS reads done

        #pragma unroll
        for (int i = 0; i < 4; ++i)
            *(float4*)&U.p2.PL[(tq * 4 + i) * PPAD + dg * 4] =
                make_float4(Pa[i][0], Pa[i][1], Pa[i][2], Pa[i][3]);
    }

    // ---- write tile 0 from GA; refill GA with tile 2 ----
    const int xw = (srow & 7) << 4;
    {
        *(uint4*)(&U.p2.a.cbuf[0][srow * 128] + ((sq * 16) ^ xw)) = ga;
        ga = *(const uint4*)(wscb + (size_t)2 * (KT * 128) + (size_t)tid * 16);
    }
    __syncthreads();                                  // S3: PL + tile0 ready

    // ---- A fragments (bf16 RNE) from PL ----
    bf16x8 A0, A1;
    {
        const float* pr = &U.p2.PL[((wid << 4) + lrow) * PPAD];
        #pragma unroll
        for (int i = 0; i < 8; ++i) {
            A0[i] = (short)rne16(bits(pr[lgrp * 8 + i]));        // d 0..31
            A1[i] = (short)rne16(bits(pr[32 + lgrp * 8 + i]));   // d 32..63
        }
    }

    // ---- filter loop over 32 tiles, depth-2 pipelined staging ----
    float m1[4], m2[4];
    #pragma unroll
    for (int r = 0; r < 4; ++r) { m1[r] = -INFINITY; m2[r] = -INFINITY; }
    uint32_t idxv = (uint32_t)(1023 - lrow);  // payload = 1023 - k

    const int xr  = (lrow & 7) << 4;
    const int bo0 = (lgrp * 16) ^ xr;
    const int bo1 = (64 + lgrp * 16) ^ xr;

    #pragma unroll 2
    for (int kt = 0; kt < NKT; ++kt) {
        const char* buf = U.p2.a.cbuf[kt & 1];
        #pragma unroll
        for (int s = 0; s < 2; ++s) {
            const char* rowp = buf + (s * 16 + lrow) * 128;
            bf16x8 B0 = *(const bf16x8*)(rowp + bo0);
            bf16x8 B1 = *(const bf16x8*)(rowp + bo1);
            f32x4 acc = {0.f, 0.f, 0.f, 0.f};
            acc = __builtin_amdgcn_mfma_f32_16x16x32_bf16(A0, B0, acc, 0, 0, 0);
            acc = __builtin_amdgcn_mfma_f32_16x16x32_bf16(A1, B1, acc, 0, 0, 0);
            #pragma unroll
            for (int r = 0; r < 4; ++r) {
                const float pf = fbits((bits(acc[r]) & 0xFFFFFC00u)
                                     | (idxv & 0x3FFu));
                m2[r] = __builtin_amdgcn_fmed3f(pf, m1[r], m2[r]);
                m1[r] = fmaxf(pf, m1[r]);
            }
            idxv -= 16u;
        }
        // write tile kt+1 (loaded >=2 iterations ago), refill with tile kt+3
        if (kt + 1 < NKT) {
            char* base = &U.p2.a.cbuf[(kt + 1) & 1][srow * 128];
            if ((kt + 1) & 1) {
                *(uint4*)(base + ((sq * 16) ^ xw)) = gb;
                if (kt + 3 < NKT)
                    gb = *(const uint4*)(wscb + (size_t)(kt + 3) * (KT * 128)
                                         + (size_t)tid * 16);
            } else {
                *(uint4*)(base + ((sq * 16) ^ xw)) = ga;
                if (kt + 3 < NKT)
                    ga = *(const uint4*)(wscb + (size_t)(kt + 3) * (KT * 128)
                                         + (size_t)tid * 16);
            }
        }
        __syncthreads();
    }
    // cbuf dead from here -> candT may alias it.

    // ---- per-lane top-2 -> candT[lane][t]; C row t = wid*16+lgrp*4+r ----
    #pragma unroll
    for (int r = 0; r < 4; ++r) {
        const int trow = (wid << 4) + (lgrp << 2) + r;
        U.p2.a.candT[lrow][trow][0] = bits(m1[r]);
        U.p2.a.candT[lrow][trow][1] = bits(m2[r]);
    }
    __syncthreads();                                  // S4: candT ready

    // ---- merge top-8 per t (4 threads/t redundantly) ----
    float sel0, sel1;
    {
        const int t = tid & 63;
        const int j = wid;
        float c1 = -INFINITY, c2 = -INFINITY, c3 = -INFINITY, c4 = -INFINITY;
        float c5 = -INFINITY, c6 = -INFINITY, c7 = -INFINITY, c8 = -INFINITY;
        for (int i = 0; i < 16; ++i) {
            const uint2 pv2 = *(const uint2*)&U.p2.a.candT[i][t][0];
            #pragma unroll
            for (int jj = 0; jj < 2; ++jj) {
                const float p = fbits(jj ? pv2.y : pv2.x);
                c8 = fmaxf(fminf(p, c7), c8);
                c7 = fmaxf(fminf(p, c6), c7);
                c6 = fmaxf(fminf(p, c5), c6);
                c5 = fmaxf(fminf(p, c4), c5);
                c4 = fmaxf(fminf(p, c3), c4);
                c3 = fmaxf(fminf(p, c2), c3);
                c2 = fmaxf(fminf(p, c1), c2);
                c1 = fmaxf(p, c1);
            }
        }
        sel0 = (j == 0) ? c1 : (j == 1) ? c3 : (j == 2) ? c5 : c7;
        sel1 = (j == 0) ? c2 : (j == 1) ? c4 : (j == 2) ? c6 : c8;
    }
    __syncthreads();                                  // S4b: candT reads done

    // ---- exact fp32 rescore (scv/sck alias candT region) ----
    {
        const int t = tid & 63;
        const int j = wid;
        const float* pr  = &U.p2.PL[t * PPAD];
        const float* cbc = cb + (size_t)c * KCB * DDIM;
        #pragma unroll
        for (int e = 0; e < 2; ++e) {
            const float sel = e ? sel1 : sel0;
            const int kj = 1023 - (int)(bits(sel) & 0x3FFu);
            const float* cbr = cbc + (size_t)kj * DDIM;
            float a0 = 0.f, a1 = 0.f, a2 = 0.f, a3 = 0.f;
            #pragma unroll
            for (int i = 0; i < 16; ++i) {
                float4 pv = *(const float4*)(pr + i * 4);
                float4 cv = *(const float4*)(cbr + i * 4);
                a0 = fmaf(pv.x, cv.x, a0); a1 = fmaf(pv.y, cv.y, a1);
                a2 = fmaf(pv.z, cv.z, a2); a3 = fmaf(pv.w, cv.w, a3);
            }
            U.p2.a.m.scv[t][2*j + e] = ((a0 + a1) + (a2 + a3)) * invn_g[kj];
            U.p2.a.m.sck[t][2*j + e] = kj;
        }
    }
    __syncthreads();                                  // S5

    if (tid < TM) {
        const int tg = t0 + tid;
        if (tg < TSTEPS) {
            float best = U.p2.a.m.scv[tid][0];
            int   bk   = U.p2.a.m.sck[tid][0];
            #pragma unroll
            for (int s2 = 1; s2 < 8; ++s2) {
                const float v = U.p2.a.m.scv[tid][s2];
                const int  kk = U.p2.a.m.sck[tid][s2];
                if (v > best || (v == best && kk < bk)) { best = v; bk = kk; }
            }
            out[((size_t)c * B + b) * TSTEPS + tg] = bk;
        }
    }
}

// ------------------------------------------------------------- fallback ----
__global__ __launch_bounds__(TPB, 2) void rpq_fallback(
    const float* __restrict__ mel, const float* __restrict__ proj,
    const float* __restrict__ cb, int* __restrict__ out)
{
    const int tid = threadIdx.x;
    const int b = blockIdx.y, c = blockIdx.z;
    const int t0 = blockIdx.x * (TPB * 2) + tid;
    const int t1 = t0 + TPB;
    const int tc0 = (t0 < TSTEPS) ? t0 : (TSTEPS - 1);
    const int tc1 = (t1 < TSTEPS) ? t1 : (TSTEPS - 1);

    __shared__ union { float projS[NMELS*DDIM]; float cbS[2][64*DDIM]; } sh;
    __shared__ float invn[KCB];
    const float* cbc = cb + (size_t)c * KCB * DDIM;
    {
        const float4* src = (const float4*)(proj + (size_t)c * NMELS * DDIM);
        float4* dst = (float4*)sh.projS;
        for (int i = tid; i < NMELS*DDIM/4; i += TPB) dst[i] = src[i];
    }
    for (int j = 0; j < KCB/TPB; ++j) {
        const int k = j*TPB + tid;
        const float4* r = (const float4*)(cbc + (size_t)k * DDIM);
        float s = 0.f;
        #pragma unroll
        for (int i = 0; i < DDIM/4; ++i) {
            float4 v = r[i]; s += v.x*v.x + v.y*v.y + v.z*v.z + v.w*v.w;
        }
        invn[k] = 1.0f / fmaxf(sqrtf(s), 1e-12f);
    }
    float4 r0, r1, r2, r3;
    { const float4* g = (const float4*)cbc;
      r0 = g[tid]; r1 = g[tid+256]; r2 = g[tid+512]; r3 = g[tid+768]; }
    __syncthreads();
    float P0[DDIM], P1[DDIM];
    #pragma unroll
    for (int d = 0; d < DDIM; ++d) { P0[d] = 0.f; P1[d] = 0.f; }
    const float* mp = mel + (size_t)b * NMELS * TSTEPS;
    for (int n = 0; n < NMELS; ++n) {
        const float m0 = mp[(size_t)n*TSTEPS + tc0];
        const float m1_ = mp[(size_t)n*TSTEPS + tc1];
        const float4* ps = (const float4*)(sh.projS + n*DDIM);
        #pragma unroll
        for (int i = 0; i < DDIM/4; ++i) {
            float4 v = ps[i];
            P0[4*i+0]=fmaf(m0,v.x,P0[4*i+0]); P0[4*i+1]=fmaf(m0,v.y,P0[4*i+1]);
            P0[4*i+2]=fmaf(m0,v.z,P0[4*i+2]); P0[4*i+3]=fmaf(m0,v.w,P0[4*i+3]);
            P1[4*i+0]=fmaf(m1_,v.x,P1[4*i+0]); P1[4*i+1]=fmaf(m1_,v.y,P1[4*i+1]);
            P1[4*i+2]=fmaf(m1_,v.z,P1[4*i+2]); P1[4*i+3]=fmaf(m1_,v.w,P1[4*i+3]);
        }
    }
    __syncthreads();
    { float4* dst = (float4*)sh.cbS[0];
      dst[tid]=r0; dst[tid+256]=r1; dst[tid+512]=r2; dst[tid+768]=r3; }
    { const float4* g = (const float4*)(cbc + (size_t)64*DDIM);
      r0=g[tid]; r1=g[tid+256]; r2=g[tid+512]; r3=g[tid+768]; }
    __syncthreads();
    float best0 = -INFINITY, best1 = -INFINITY; int bi0 = 0, bi1 = 0;
    for (int kt = 0; kt < KCB/64; ++kt) {
        const int cur = kt & 1;
        const float* base = sh.cbS[cur];
        const int kbase = kt * 64;
        #pragma unroll 2
        for (int kk = 0; kk < 64; ++kk) {
            const float4* row = (const float4*)(base + kk*DDIM);
            float a0=0,a1=0,a2=0,a3=0,b0=0,b1=0,b2=0,b3=0;
            #pragma unroll
            for (int i = 0; i < DDIM/4; ++i) {
                float4 v = row[i];
                a0=fmaf(P0[4*i+0],v.x,a0); a1=fmaf(P0[4*i+1],v.y,a1);
                a2=fmaf(P0[4*i+2],v.z,a2); a3=fmaf(P0[4*i+3],v.w,a3);
                b0=fmaf(P1[4*i+0],v.x,b0); b1=fmaf(P1[4*i+1],v.y,b1);
                b2=fmaf(P1[4*i+2],v.z,b2); b3=fmaf(P1[4*i+3],v.w,b3);
            }
            const int k = kbase + kk;
            const float w = invn[k];
            const float s0 = ((a0+a1)+(a2+a3))*w;
            const float s1 = ((b0+b1)+(b2+b3))*w;
            if (s0 > best0) { best0 = s0; bi0 = k; }
            if (s1 > best1) { best1 = s1; bi1 = k; }
        }
        if (kt + 1 < KCB/64) {
            float4* dst = (float4*)sh.cbS[cur ^ 1];
            dst[tid]=r0; dst[tid+256]=r1; dst[tid+512]=r2; dst[tid+768]=r3;
            if (kt + 2 < KCB/64) {
                const float4* g = (const float4*)(cbc + (size_t)(kt+2)*64*DDIM);
                r0=g[tid]; r1=g[tid+256]; r2=g[tid+512]; r3=g[tid+768];
            }
        }
        __syncthreads();
    }
    const size_t ob = ((size_t)c * B + b) * TSTEPS;
    if (t0 < TSTEPS) out[ob + t0] = bi0;
    if (t1 < TSTEPS) out[ob + t1] = bi1;
}

// --------------------------------------------------------------- launch ----
extern "C" void kernel_launch(void* const* d_in, const int* in_sizes, int n_in,
                              void* d_out, int out_size, void* d_ws, size_t ws_size,
                              hipStream_t stream) {
    const float* mel  = (const float*)d_in[0];
    const float* proj = (const float*)d_in[1];
    const float* cb   = (const float*)d_in[2];
    int* out = (int*)d_out;

    if (ws_size >= (size_t)WS_NEEDED) {   // proven true on this harness (R4)
        float* ws = (float*)d_ws;
        rpq_prep<<<dim3((NCB*KCB + TPB - 1)/TPB), dim3(TPB), 0, stream>>>(cb, ws);
        dim3 grid((TSTEPS + TM - 1) / TM, B, NCB);     // (63, 32, 2)
        rpq_main<<<grid, dim3(TPB), 0, stream>>>(mel, proj, cb, ws, out);
    } else {
        dim3 grid((TSTEPS + TPB*2 - 1) / (TPB*2), B, NCB);
        rpq_fallback<<<grid, dim3(TPB), 0, stream>>>(mel, proj, cb, out);
    }
}

// Round 13
// 179.217 us; speedup vs baseline: 1.0661x; 1.0661x over previous
//
#include <hip/hip_runtime.h>
#include <hip/hip_bf16.h>
#include <math.h>
#include <stdint.h>

// RandomProjectionQuantizer — bf16 MFMA filter + exact fp32 top-8 rescore.
//   mel [32,80,4000] f32, proj [2,80,64] f32, codebooks [2,1024,64] f32
//   codes[c,b,t] = argmax_k ( (mel[b,:,t] @ proj[c]) . cb[c,k,:]/||cb[c,k]|| )
//
// R13 = R12 with __launch_bounds__(256,3). Empirical hipcc behavior on this
// harness: VGPR cap = 512/(2*arg), granularity 8 (measured: arg 4/5/6 ->
// 64/48/40). arg=6 starved the allocator to 40 VGPRs -> 84MB scratch spill
// (R12's regression). arg=3 -> cap 85 >= live set (~64-80): no spill, and
// LDS 25088B allows 6 blocks/CU = 24 waves (75%).
// Everything else byte-identical to R12 (passed, absmax 0).

#define B      32
#define NMELS  80
#define TSTEPS 4000
#define NCB    2
#define KCB    1024
#define DDIM   64
#define TPB    256
#define TM     64            // t's per block (16 per wave)
#define KT     32            // codebook rows per LDS tile (4 KB bf16)
#define NKT    (KCB / KT)    // 32 tiles
#define PPAD   66            // P row stride (floats) — proven

typedef short bf16x8 __attribute__((ext_vector_type(8)));
typedef float f32x4  __attribute__((ext_vector_type(4)));

#define WS_CB_OFF   8192                         // bytes: invn table first
#define WS_NEEDED   (8192 + NCB*KCB*DDIM*2)      // 270336 (proven fits, R4)

static __device__ __forceinline__ uint32_t bits(float f) {
    return __builtin_bit_cast(uint32_t, f);
}
static __device__ __forceinline__ float fbits(uint32_t u) {
    return __builtin_bit_cast(float, u);
}
// round-to-nearest-even f32 -> bf16 (returns low 16 bits)
static __device__ __forceinline__ uint32_t rne16(uint32_t u) {
    return (u + 0x7FFFu + ((u >> 16) & 1u)) >> 16;
}

// ---------------------------------------------------------------- prep ----
__global__ __launch_bounds__(TPB) void rpq_prep(const float* __restrict__ cb,
                                                float* __restrict__ ws)
{
    const int idx = blockIdx.x * TPB + threadIdx.x;
    if (idx >= NCB * KCB) return;

    const float4* row = (const float4*)(cb + (size_t)idx * DDIM);
    float4 v[16];
    float ss = 0.f;
    #pragma unroll
    for (int i = 0; i < 16; ++i) {
        v[i] = row[i];
        ss += v[i].x*v[i].x + v[i].y*v[i].y + v[i].z*v[i].z + v[i].w*v[i].w;
    }
    const float inv = 1.0f / fmaxf(sqrtf(ss), 1e-12f);
    ws[idx] = inv;

    uint32_t dw[32];
    #pragma unroll
    for (int i = 0; i < 16; ++i) {
        dw[2*i]   = rne16(bits(v[i].x * inv)) | (rne16(bits(v[i].y * inv)) << 16);
        dw[2*i+1] = rne16(bits(v[i].z * inv)) | (rne16(bits(v[i].w * inv)) << 16);
    }
    uint4* dst = (uint4*)((char*)ws + WS_CB_OFF + (size_t)idx * 128);
    #pragma unroll
    for (int i = 0; i < 8; ++i)
        dst[i] = make_uint4(dw[4*i], dw[4*i+1], dw[4*i+2], dw[4*i+3]);
}

// ---------------------------------------------------------------- main ----
__global__ __launch_bounds__(TPB, 3) void rpq_main(
    const float* __restrict__ mel,
    const float* __restrict__ proj,
    const float* __restrict__ cb,
    const float* __restrict__ ws,
    int* __restrict__ out)
{
    const int tid  = threadIdx.x;
    const int b    = blockIdx.y;
    const int c    = blockIdx.z;
    const int t0   = blockIdx.x * TM;

    const int l    = tid & 63;
    const int wid  = tid >> 6;      // wave 0..3
    const int lrow = l & 15;        // A/B row-col within 16x16
    const int lgrp = l >> 4;        // k-octet group 0..3

    // projS: phase-1 only. cbuf/PL written after S2. candT aliases cbuf
    // (written after filter's final barrier); scv/sck alias candT (written
    // after the S4b barrier that ends all candT reads).
    __shared__ union __align__(16) {
        float projS[NMELS * DDIM];              // 20480 B
        struct {
            union {
                char     cbuf[2][KT * 128];     // 8192 B (bf16 dbuf, swizzled)
                uint32_t candT[16][TM][2];      // 8192 B (transposed top-2)
                struct {
                    float scv[TM][9];           // 2304 B
                    int   sck[TM][9];           // 2304 B
                } m;
            } a;
            float PL[TM * PPAD];                // 16896 B
        } p2;
    } U;                                        // total 25088 B -> 6 blocks/CU

    const char*  wscb   = (const char*)ws + WS_CB_OFF + (size_t)c * (KCB * 128);
    const float* invn_g = ws + (size_t)c * KCB;

    // ---- stage proj[c] into LDS ----
    {
        const float4* src = (const float4*)(proj + (size_t)c * NMELS * DDIM);
        float4* dst = (float4*)U.projS;
        for (int i = tid; i < NMELS * DDIM / 4; i += TPB) dst[i] = src[i];
    }
    __syncthreads();                                  // S1

    // ---- DEPTH-2 prefetch: tiles 0 and 1 loaded before phase-1 ----
    const int srow = tid >> 3;     // staging row 0..31
    const int sq   = tid & 7;      // 16B slot in 128B row
    uint4 ga, gb;
    ga = *(const uint4*)(wscb + (size_t)tid * 16);                    // tile 0
    gb = *(const uint4*)(wscb + (size_t)KT * 128 + (size_t)tid * 16); // tile 1

    // ---- phase 1: P[t][d]; thread = (tq = tid&15 -> 4 t's, dg = tid>>4) ----
    {
        const int tq = tid & 15;
        const int dg = tid >> 4;
        const int tbase  = t0 + tq * 4;
        const int tb_c   = (tbase <= TSTEPS - 4) ? tbase : (TSTEPS - 4);
        const float* mp  = mel + (size_t)b * NMELS * TSTEPS + tb_c;

        float Pa[4][4];
        #pragma unroll
        for (int i = 0; i < 4; ++i)
            #pragma unroll
            for (int j = 0; j < 4; ++j) Pa[i][j] = 0.f;

        for (int n = 0; n < NMELS; ++n) {
            const float4 m4 = *(const float4*)(mp + (size_t)n * TSTEPS);
            const float4 w  = *(const float4*)&U.projS[n * DDIM + dg * 4];
            Pa[0][0] = fmaf(m4.x, w.x, Pa[0][0]); Pa[0][1] = fmaf(m4.x, w.y, Pa[0][1]);
            Pa[0][2] = fmaf(m4.x, w.z, Pa[0][2]); Pa[0][3] = fmaf(m4.x, w.w, Pa[0][3]);
            Pa[1][0] = fmaf(m4.y, w.x, Pa[1][0]); Pa[1][1] = fmaf(m4.y, w.y, Pa[1][1]);
            Pa[1][2] = fmaf(m4.y, w.z, Pa[1][2]); Pa[1][3] = fmaf(m4.y, w.w, Pa[1][3]);
            Pa[2][0] = fmaf(m4.z, w.x, Pa[2][0]); Pa[2][1] = fmaf(m4.z, w.y, Pa[2][1]);
            Pa[2][2] = fmaf(m4.z, w.z, Pa[2][2]); Pa[2][3] = fmaf(m4.z, w.w, Pa[2][3]);
            Pa[3][0] = fmaf(m4.w, w.x, Pa[3][0]); Pa[3][1] = fmaf(m4.w, w.y, Pa[3][1]);
            Pa[3][2] = fmaf(m4.w, w.z, Pa[3][2]); Pa[3][3] = fmaf(m4.w, w.w, Pa[3][3]);
        }
        __syncthreads();                              // S2: projS reads done

        #pragma unroll
        for (int i = 0; i < 4; ++i)
            *(float4*)&U.p2.PL[(tq * 4 + i) * PPAD + dg * 4] =
                make_float4(Pa[i][0], Pa[i][1], Pa[i][2], Pa[i][3]);
    }

    // ---- write tile 0 from GA; refill GA with tile 2 ----
    const int xw = (srow & 7) << 4;
    {
        *(uint4*)(&U.p2.a.cbuf[0][srow * 128] + ((sq * 16) ^ xw)) = ga;
        ga = *(const uint4*)(wscb + (size_t)2 * (KT * 128) + (size_t)tid * 16);
    }
    __syncthreads();                                  // S3: PL + tile0 ready

    // ---- A fragments (bf16 RNE) from PL ----
    bf16x8 A0, A1;
    {
        const float* pr = &U.p2.PL[((wid << 4) + lrow) * PPAD];
        #pragma unroll
        for (int i = 0; i < 8; ++i) {
            A0[i] = (short)rne16(bits(pr[lgrp * 8 + i]));        // d 0..31
            A1[i] = (short)rne16(bits(pr[32 + lgrp * 8 + i]));   // d 32..63
        }
    }

    // ---- filter loop over 32 tiles, depth-2 pipelined staging ----
    float m1[4], m2[4];
    #pragma unroll
    for (int r = 0; r < 4; ++r) { m1[r] = -INFINITY; m2[r] = -INFINITY; }
    uint32_t idxv = (uint32_t)(1023 - lrow);  // payload = 1023 - k

    const int xr  = (lrow & 7) << 4;
    const int bo0 = (lgrp * 16) ^ xr;
    const int bo1 = (64 + lgrp * 16) ^ xr;

    #pragma unroll 2
    for (int kt = 0; kt < NKT; ++kt) {
        const char* buf = U.p2.a.cbuf[kt & 1];
        #pragma unroll
        for (int s = 0; s < 2; ++s) {
            const char* rowp = buf + (s * 16 + lrow) * 128;
            bf16x8 B0 = *(const bf16x8*)(rowp + bo0);
            bf16x8 B1 = *(const bf16x8*)(rowp + bo1);
            f32x4 acc = {0.f, 0.f, 0.f, 0.f};
            acc = __builtin_amdgcn_mfma_f32_16x16x32_bf16(A0, B0, acc, 0, 0, 0);
            acc = __builtin_amdgcn_mfma_f32_16x16x32_bf16(A1, B1, acc, 0, 0, 0);
            #pragma unroll
            for (int r = 0; r < 4; ++r) {
                const float pf = fbits((bits(acc[r]) & 0xFFFFFC00u)
                                     | (idxv & 0x3FFu));
                m2[r] = __builtin_amdgcn_fmed3f(pf, m1[r], m2[r]);
                m1[r] = fmaxf(pf, m1[r]);
            }
            idxv -= 16u;
        }
        // write tile kt+1 (loaded >=2 iterations ago), refill with tile kt+3
        if (kt + 1 < NKT) {
            char* base = &U.p2.a.cbuf[(kt + 1) & 1][srow * 128];
            if ((kt + 1) & 1) {
                *(uint4*)(base + ((sq * 16) ^ xw)) = gb;
                if (kt + 3 < NKT)
                    gb = *(const uint4*)(wscb + (size_t)(kt + 3) * (KT * 128)
                                         + (size_t)tid * 16);
            } else {
                *(uint4*)(base + ((sq * 16) ^ xw)) = ga;
                if (kt + 3 < NKT)
                    ga = *(const uint4*)(wscb + (size_t)(kt + 3) * (KT * 128)
                                         + (size_t)tid * 16);
            }
        }
        __syncthreads();
    }
    // cbuf dead from here -> candT may alias it.

    // ---- per-lane top-2 -> candT[lane][t]; C row t = wid*16+lgrp*4+r ----
    #pragma unroll
    for (int r = 0; r < 4; ++r) {
        const int trow = (wid << 4) + (lgrp << 2) + r;
        U.p2.a.candT[lrow][trow][0] = bits(m1[r]);
        U.p2.a.candT[lrow][trow][1] = bits(m2[r]);
    }
    __syncthreads();                                  // S4: candT ready

    // ---- merge top-8 per t (4 threads/t redundantly) ----
    float sel0, sel1;
    {
        const int t = tid & 63;
        const int j = wid;
        float c1 = -INFINITY, c2 = -INFINITY, c3 = -INFINITY, c4 = -INFINITY;
        float c5 = -INFINITY, c6 = -INFINITY, c7 = -INFINITY, c8 = -INFINITY;
        for (int i = 0; i < 16; ++i) {
            const uint2 pv2 = *(const uint2*)&U.p2.a.candT[i][t][0];
            #pragma unroll
            for (int jj = 0; jj < 2; ++jj) {
                const float p = fbits(jj ? pv2.y : pv2.x);
                c8 = fmaxf(fminf(p, c7), c8);
                c7 = fmaxf(fminf(p, c6), c7);
                c6 = fmaxf(fminf(p, c5), c6);
                c5 = fmaxf(fminf(p, c4), c5);
                c4 = fmaxf(fminf(p, c3), c4);
                c3 = fmaxf(fminf(p, c2), c3);
                c2 = fmaxf(fminf(p, c1), c2);
                c1 = fmaxf(p, c1);
            }
        }
        sel0 = (j == 0) ? c1 : (j == 1) ? c3 : (j == 2) ? c5 : c7;
        sel1 = (j == 0) ? c2 : (j == 1) ? c4 : (j == 2) ? c6 : c8;
    }
    __syncthreads();                                  // S4b: candT reads done

    // ---- exact fp32 rescore (scv/sck alias candT region) ----
    {
        const int t = tid & 63;
        const int j = wid;
        const float* pr  = &U.p2.PL[t * PPAD];
        const float* cbc = cb + (size_t)c * KCB * DDIM;
        #pragma unroll
        for (int e = 0; e < 2; ++e) {
            const float sel = e ? sel1 : sel0;
            const int kj = 1023 - (int)(bits(sel) & 0x3FFu);
            const float* cbr = cbc + (size_t)kj * DDIM;
            float a0 = 0.f, a1 = 0.f, a2 = 0.f, a3 = 0.f;
            #pragma unroll
            for (int i = 0; i < 16; ++i) {
                float4 pv = *(const float4*)(pr + i * 4);
                float4 cv = *(const float4*)(cbr + i * 4);
                a0 = fmaf(pv.x, cv.x, a0); a1 = fmaf(pv.y, cv.y, a1);
                a2 = fmaf(pv.z, cv.z, a2); a3 = fmaf(pv.w, cv.w, a3);
            }
            U.p2.a.m.scv[t][2*j + e] = ((a0 + a1) + (a2 + a3)) * invn_g[kj];
            U.p2.a.m.sck[t][2*j + e] = kj;
        }
    }
    __syncthreads();                                  // S5

    if (tid < TM) {
        const int tg = t0 + tid;
        if (tg < TSTEPS) {
            float best = U.p2.a.m.scv[tid][0];
            int   bk   = U.p2.a.m.sck[tid][0];
            #pragma unroll
            for (int s2 = 1; s2 < 8; ++s2) {
                const float v = U.p2.a.m.scv[tid][s2];
                const int  kk = U.p2.a.m.sck[tid][s2];
                if (v > best || (v == best && kk < bk)) { best = v; bk = kk; }
            }
            out[((size_t)c * B + b) * TSTEPS + tg] = bk;
        }
    }
}

// ------------------------------------------------------------- fallback ----
__global__ __launch_bounds__(TPB, 2) void rpq_fallback(
    const float* __restrict__ mel, const float* __restrict__ proj,
    const float* __restrict__ cb, int* __restrict__ out)
{
    const int tid = threadIdx.x;
    const int b = blockIdx.y, c = blockIdx.z;
    const int t0 = blockIdx.x * (TPB * 2) + tid;
    const int t1 = t0 + TPB;
    const int tc0 = (t0 < TSTEPS) ? t0 : (TSTEPS - 1);
    const int tc1 = (t1 < TSTEPS) ? t1 : (TSTEPS - 1);

    __shared__ union { float projS[NMELS*DDIM]; float cbS[2][64*DDIM]; } sh;
    __shared__ float invn[KCB];
    const float* cbc = cb + (size_t)c * KCB * DDIM;
    {
        const float4* src = (const float4*)(proj + (size_t)c * NMELS * DDIM);
        float4* dst = (float4*)sh.projS;
        for (int i = tid; i < NMELS*DDIM/4; i += TPB) dst[i] = src[i];
    }
    for (int j = 0; j < KCB/TPB; ++j) {
        const int k = j*TPB + tid;
        const float4* r = (const float4*)(cbc + (size_t)k * DDIM);
        float s = 0.f;
        #pragma unroll
        for (int i = 0; i < DDIM/4; ++i) {
            float4 v = r[i]; s += v.x*v.x + v.y*v.y + v.z*v.z + v.w*v.w;
        }
        invn[k] = 1.0f / fmaxf(sqrtf(s), 1e-12f);
    }
    float4 r0, r1, r2, r3;
    { const float4* g = (const float4*)cbc;
      r0 = g[tid]; r1 = g[tid+256]; r2 = g[tid+512]; r3 = g[tid+768]; }
    __syncthreads();
    float P0[DDIM], P1[DDIM];
    #pragma unroll
    for (int d = 0; d < DDIM; ++d) { P0[d] = 0.f; P1[d] = 0.f; }
    const float* mp = mel + (size_t)b * NMELS * TSTEPS;
    for (int n = 0; n < NMELS; ++n) {
        const float m0 = mp[(size_t)n*TSTEPS + tc0];
        const float m1_ = mp[(size_t)n*TSTEPS + tc1];
        const float4* ps = (const float4*)(sh.projS + n*DDIM);
        #pragma unroll
        for (int i = 0; i < DDIM/4; ++i) {
            float4 v = ps[i];
            P0[4*i+0]=fmaf(m0,v.x,P0[4*i+0]); P0[4*i+1]=fmaf(m0,v.y,P0[4*i+1]);
            P0[4*i+2]=fmaf(m0,v.z,P0[4*i+2]); P0[4*i+3]=fmaf(m0,v.w,P0[4*i+3]);
            P1[4*i+0]=fmaf(m1_,v.x,P1[4*i+0]); P1[4*i+1]=fmaf(m1_,v.y,P1[4*i+1]);
            P1[4*i+2]=fmaf(m1_,v.z,P1[4*i+2]); P1[4*i+3]=fmaf(m1_,v.w,P1[4*i+3]);
        }
    }
    __syncthreads();
    { float4* dst = (float4*)sh.cbS[0];
      dst[tid]=r0; dst[tid+256]=r1; dst[tid+512]=r2; dst[tid+768]=r3; }
    { const float4* g = (const float4*)(cbc + (size_t)64*DDIM);
      r0=g[tid]; r1=g[tid+256]; r2=g[tid+512]; r3=g[tid+768]; }
    __syncthreads();
    float best0 = -INFINITY, best1 = -INFINITY; int bi0 = 0, bi1 = 0;
    for (int kt = 0; kt < KCB/64; ++kt) {
        const int cur = kt & 1;
        const float* base = sh.cbS[cur];
        const int kbase = kt * 64;
        #pragma unroll 2
        for (int kk = 0; kk < 64; ++kk) {
            const float4* row = (const float4*)(base + kk*DDIM);
            float a0=0,a1=0,a2=0,a3=0,b0=0,b1=0,b2=0,b3=0;
            #pragma unroll
            for (int i = 0; i < DDIM/4; ++i) {
                float4 v = row[i];
                a0=fmaf(P0[4*i+0],v.x,a0); a1=fmaf(P0[4*i+1],v.y,a1);
                a2=fmaf(P0[4*i+2],v.z,a2); a3=fmaf(P0[4*i+3],v.w,a3);
                b0=fmaf(P1[4*i+0],v.x,b0); b1=fmaf(P1[4*i+1],v.y,b1);
                b2=fmaf(P1[4*i+2],v.z,b2); b3=fmaf(P1[4*i+3],v.w,b3);
            }
            const int k = kbase + kk;
            const float w = invn[k];
            const float s0 = ((a0+a1)+(a2+a3))*w;
            const float s1 = ((b0+b1)+(b2+b3))*w;
            if (s0 > best0) { best0 = s0; bi0 = k; }
            if (s1 > best1) { best1 = s1; bi1 = k; }
        }
        if (kt + 1 < KCB/64) {
            float4* dst = (float4*)sh.cbS[cur ^ 1];
            dst[tid]=r0; dst[tid+256]=r1; dst[tid+512]=r2; dst[tid+768]=r3;
            if (kt + 2 < KCB/64) {
                const float4* g = (const float4*)(cbc + (size_t)(kt+2)*64*DDIM);
                r0=g[tid]; r1=g[tid+256]; r2=g[tid+512]; r3=g[tid+768];
            }
        }
        __syncthreads();
    }
    const size_t ob = ((size_t)c * B + b) * TSTEPS;
    if (t0 < TSTEPS) out[ob + t0] = bi0;
    if (t1 < TSTEPS) out[ob + t1] = bi1;
}

// --------------------------------------------------------------- launch ----
extern "C" void kernel_launch(void* const* d_in, const int* in_sizes, int n_in,
                              void* d_out, int out_size, void* d_ws, size_t ws_size,
                              hipStream_t stream) {
    const float* mel  = (const float*)d_in[0];
    const float* proj = (const float*)d_in[1];
    const float* cb   = (const float*)d_in[2];
    int* out = (int*)d_out;

    if (ws_size >= (size_t)WS_NEEDED) {   // proven true on this harness (R4)
        float* ws = (float*)d_ws;
        rpq_prep<<<dim3((NCB*KCB + TPB - 1)/TPB), dim3(TPB), 0, stream>>>(cb, ws);
        dim3 grid((TSTEPS + TM - 1) / TM, B, NCB);     // (63, 32, 2)
        rpq_main<<<grid, dim3(TPB), 0, stream>>>(mel, proj, cb, ws, out);
    } else {
        dim3 grid((TSTEPS + TPB*2 - 1) / (TPB*2), B, NCB);
        rpq_fallback<<<grid, dim3(TPB), 0, stream>>>(mel, proj, cb, out);
    }
}

// Round 14
// 171.034 us; speedup vs baseline: 1.1171x; 1.0478x over previous
//
#include <hip/hip_runtime.h>
#include <hip/hip_bf16.h>
#include <math.h>
#include <stdint.h>

// RandomProjectionQuantizer — bf16 MFMA filter + exact fp32 top-8 rescore.
//   mel [32,80,4000] f32, proj [2,80,64] f32, codebooks [2,1024,64] f32
//   codes[c,b,t] = argmax_k ( (mel[b,:,t] @ proj[c]) . cb[c,k,:]/||cb[c,k]|| )
//
// R14: TM=128 (2x work per block) to amortize per-t overheads:
//   - phase-1: 8t x 4d per thread, TWO adjacent mel float4 loads per n
//     (2x memory-level parallelism on the latency-bound mel stream);
//   - each wave holds 2 A-frag pairs (rows wid*16 and 64+wid*16): each
//     B-fragment read feeds 4 MFMAs; barriers/staging per-t halved;
//   - merge redundancy 4x -> 2x.
//   __launch_bounds__(256,3): VGPR cap 85 (empirical cap=512/(2*arg));
//   R11 sat at cap 64 -> squeezed. LDS 50176 -> 3 blocks/CU.
// Staging/swizzle/MFMA-mapping/top-2/rescore = proven lineage, re-indexed.

#define B      32
#define NMELS  80
#define TSTEPS 4000
#define NCB    2
#define KCB    1024
#define DDIM   64
#define TPB    256
#define TM     128           // t's per block (2 x 16 per wave)
#define KT     64            // codebook rows per LDS tile (8 KB bf16)
#define NKT    (KCB / KT)    // 16 tiles
#define PPAD   66            // P row stride (floats) — proven

typedef short bf16x8 __attribute__((ext_vector_type(8)));
typedef float f32x4  __attribute__((ext_vector_type(4)));

#define WS_CB_OFF   8192                         // bytes: invn table first
#define WS_NEEDED   (8192 + NCB*KCB*DDIM*2)      // 270336 (proven fits, R4)

static __device__ __forceinline__ uint32_t bits(float f) {
    return __builtin_bit_cast(uint32_t, f);
}
static __device__ __forceinline__ float fbits(uint32_t u) {
    return __builtin_bit_cast(float, u);
}
// round-to-nearest-even f32 -> bf16 (returns low 16 bits)
static __device__ __forceinline__ uint32_t rne16(uint32_t u) {
    return (u + 0x7FFFu + ((u >> 16) & 1u)) >> 16;
}

// ---------------------------------------------------------------- prep ----
__global__ __launch_bounds__(TPB) void rpq_prep(const float* __restrict__ cb,
                                                float* __restrict__ ws)
{
    const int idx = blockIdx.x * TPB + threadIdx.x;
    if (idx >= NCB * KCB) return;

    const float4* row = (const float4*)(cb + (size_t)idx * DDIM);
    float4 v[16];
    float ss = 0.f;
    #pragma unroll
    for (int i = 0; i < 16; ++i) {
        v[i] = row[i];
        ss += v[i].x*v[i].x + v[i].y*v[i].y + v[i].z*v[i].z + v[i].w*v[i].w;
    }
    const float inv = 1.0f / fmaxf(sqrtf(ss), 1e-12f);
    ws[idx] = inv;

    uint32_t dw[32];
    #pragma unroll
    for (int i = 0; i < 16; ++i) {
        dw[2*i]   = rne16(bits(v[i].x * inv)) | (rne16(bits(v[i].y * inv)) << 16);
        dw[2*i+1] = rne16(bits(v[i].z * inv)) | (rne16(bits(v[i].w * inv)) << 16);
    }
    uint4* dst = (uint4*)((char*)ws + WS_CB_OFF + (size_t)idx * 128);
    #pragma unroll
    for (int i = 0; i < 8; ++i)
        dst[i] = make_uint4(dw[4*i], dw[4*i+1], dw[4*i+2], dw[4*i+3]);
}

// ---------------------------------------------------------------- main ----
__global__ __launch_bounds__(TPB, 3) void rpq_main(
    const float* __restrict__ mel,
    const float* __restrict__ proj,
    const float* __restrict__ cb,
    const float* __restrict__ ws,
    int* __restrict__ out)
{
    const int tid  = threadIdx.x;
    const int b    = blockIdx.y;
    const int c    = blockIdx.z;
    const int t0   = blockIdx.x * TM;

    const int l    = tid & 63;
    const int wid  = tid >> 6;      // wave 0..3
    const int lrow = l & 15;        // A/B row-col within 16x16
    const int lgrp = l >> 4;        // k-octet group 0..3

    // projS: phase-1 only. cbuf/PL written after S2. candT aliases cbuf
    // (written after filter's final barrier); scv/sck alias candT (written
    // after S4b, which ends all candT reads).
    __shared__ union __align__(16) {
        float projS[NMELS * DDIM];              // 20480 B
        struct {
            union {
                char     cbuf[2][KT * 128];     // 16384 B (bf16 dbuf, swizzled)
                uint32_t candT[16][TM][2];      // 16384 B (transposed top-2)
                struct {
                    float scv[TM][9];           // 4608 B
                    int   sck[TM][9];           // 4608 B
                } m;
            } a;
            float PL[TM * PPAD];                // 33792 B
        } p2;
    } U;                                        // total 50176 B -> 3 blocks/CU

    const char*  wscb   = (const char*)ws + WS_CB_OFF + (size_t)c * (KCB * 128);
    const float* invn_g = ws + (size_t)c * KCB;

    // ---- stage proj[c] into LDS ----
    {
        const float4* src = (const float4*)(proj + (size_t)c * NMELS * DDIM);
        float4* dst = (float4*)U.projS;
        for (int i = tid; i < NMELS * DDIM / 4; i += TPB) dst[i] = src[i];
    }
    __syncthreads();                                  // S1

    // ---- depth-2 prefetch: tiles 0 and 1 before phase-1 (R11-proven) ----
    const int srow = tid >> 2;     // staging row 0..63
    const int sq   = tid & 3;      // 32-byte quarter
    uint4 ra0, ra1, rb0, rb1;
    {
        const uint4* gp0 = (const uint4*)(wscb + (size_t)srow * 128 + sq * 32);
        ra0 = gp0[0]; ra1 = gp0[1];                   // tile 0 -> RA
        const uint4* gp1 = (const uint4*)(wscb + (size_t)KT * 128
                                          + (size_t)srow * 128 + sq * 32);
        rb0 = gp1[0]; rb1 = gp1[1];                   // tile 1 -> RB
    }

    // ---- phase 1: thread = (tq = tid&15 -> 8 t's, dg = tid>>4 -> 4 d's) ----
    {
        const int tq = tid & 15;
        const int dg = tid >> 4;
        const int tbase  = t0 + tq * 8;
        const int tb_c   = (tbase <= TSTEPS - 8) ? tbase : (TSTEPS - 8);
        const float* mp  = mel + (size_t)b * NMELS * TSTEPS + tb_c;

        float Pa[8][4];
        #pragma unroll
        for (int i = 0; i < 8; ++i)
            #pragma unroll
            for (int j = 0; j < 4; ++j) Pa[i][j] = 0.f;

        for (int n = 0; n < NMELS; ++n) {
            const float4 mA = *(const float4*)(mp + (size_t)n * TSTEPS);
            const float4 mB = *(const float4*)(mp + (size_t)n * TSTEPS + 4);
            const float4 w  = *(const float4*)&U.projS[n * DDIM + dg * 4];
            Pa[0][0]=fmaf(mA.x,w.x,Pa[0][0]); Pa[0][1]=fmaf(mA.x,w.y,Pa[0][1]);
            Pa[0][2]=fmaf(mA.x,w.z,Pa[0][2]); Pa[0][3]=fmaf(mA.x,w.w,Pa[0][3]);
            Pa[1][0]=fmaf(mA.y,w.x,Pa[1][0]); Pa[1][1]=fmaf(mA.y,w.y,Pa[1][1]);
            Pa[1][2]=fmaf(mA.y,w.z,Pa[1][2]); Pa[1][3]=fmaf(mA.y,w.w,Pa[1][3]);
            Pa[2][0]=fmaf(mA.z,w.x,Pa[2][0]); Pa[2][1]=fmaf(mA.z,w.y,Pa[2][1]);
            Pa[2][2]=fmaf(mA.z,w.z,Pa[2][2]); Pa[2][3]=fmaf(mA.z,w.w,Pa[2][3]);
            Pa[3][0]=fmaf(mA.w,w.x,Pa[3][0]); Pa[3][1]=fmaf(mA.w,w.y,Pa[3][1]);
            Pa[3][2]=fmaf(mA.w,w.z,Pa[3][2]); Pa[3][3]=fmaf(mA.w,w.w,Pa[3][3]);
            Pa[4][0]=fmaf(mB.x,w.x,Pa[4][0]); Pa[4][1]=fmaf(mB.x,w.y,Pa[4][1]);
            Pa[4][2]=fmaf(mB.x,w.z,Pa[4][2]); Pa[4][3]=fmaf(mB.x,w.w,Pa[4][3]);
            Pa[5][0]=fmaf(mB.y,w.x,Pa[5][0]); Pa[5][1]=fmaf(mB.y,w.y,Pa[5][1]);
            Pa[5][2]=fmaf(mB.y,w.z,Pa[5][2]); Pa[5][3]=fmaf(mB.y,w.w,Pa[5][3]);
            Pa[6][0]=fmaf(mB.z,w.x,Pa[6][0]); Pa[6][1]=fmaf(mB.z,w.y,Pa[6][1]);
            Pa[6][2]=fmaf(mB.z,w.z,Pa[6][2]); Pa[6][3]=fmaf(mB.z,w.w,Pa[6][3]);
            Pa[7][0]=fmaf(mB.w,w.x,Pa[7][0]); Pa[7][1]=fmaf(mB.w,w.y,Pa[7][1]);
            Pa[7][2]=fmaf(mB.w,w.z,Pa[7][2]); Pa[7][3]=fmaf(mB.w,w.w,Pa[7][3]);
        }
        __syncthreads();                              // S2: projS reads done

        #pragma unroll
        for (int i = 0; i < 8; ++i)
            *(float4*)&U.p2.PL[(tq * 8 + i) * PPAD + dg * 4] =
                make_float4(Pa[i][0], Pa[i][1], Pa[i][2], Pa[i][3]);
    }

    // ---- write tile 0 from RA; refill RA with tile 2 ----
    const int xw = (srow & 7) << 4;
    {
        char* base = &U.p2.a.cbuf[0][srow * 128];
        *(uint4*)(base + ((sq * 32)      ^ xw)) = ra0;
        *(uint4*)(base + ((sq * 32 + 16) ^ xw)) = ra1;
        const uint4* gp = (const uint4*)(wscb + (size_t)2 * (KT * 128)
                                         + (size_t)srow * 128 + sq * 32);
        ra0 = gp[0]; ra1 = gp[1];                     // tile 2 -> RA
    }
    __syncthreads();                                  // S3: PL + tile0 ready

    // ---- A fragments (bf16 RNE): 2 pairs per wave (t-halves L/H) ----
    bf16x8 A0[2], A1[2];
    #pragma unroll
    for (int p = 0; p < 2; ++p) {
        const float* pr = &U.p2.PL[(p * 64 + (wid << 4) + lrow) * PPAD];
        #pragma unroll
        for (int i = 0; i < 8; ++i) {
            A0[p][i] = (short)rne16(bits(pr[lgrp * 8 + i]));        // d 0..31
            A1[p][i] = (short)rne16(bits(pr[32 + lgrp * 8 + i]));   // d 32..63
        }
    }

    // ---- filter over 16 tiles; each B-pair feeds 4 MFMAs (2 t-halves) ----
    float m1[2][4], m2[2][4];
    #pragma unroll
    for (int p = 0; p < 2; ++p)
        #pragma unroll
        for (int r = 0; r < 4; ++r) { m1[p][r] = -INFINITY; m2[p][r] = -INFINITY; }
    uint32_t idxv = (uint32_t)(1023 - lrow);  // payload = 1023 - k

    const int xr  = (lrow & 7) << 4;
    const int bo0 = (lgrp * 16) ^ xr;
    const int bo1 = (64 + lgrp * 16) ^ xr;

    #pragma unroll 2
    for (int kt = 0; kt < NKT; ++kt) {
        const char* buf = U.p2.a.cbuf[kt & 1];
        #pragma unroll
        for (int s = 0; s < 4; ++s) {
            const char* rowp = buf + (s * 16 + lrow) * 128;
            bf16x8 B0 = *(const bf16x8*)(rowp + bo0);
            bf16x8 B1 = *(const bf16x8*)(rowp + bo1);
            f32x4 accL = {0.f, 0.f, 0.f, 0.f};
            f32x4 accH = {0.f, 0.f, 0.f, 0.f};
            accL = __builtin_amdgcn_mfma_f32_16x16x32_bf16(A0[0], B0, accL, 0, 0, 0);
            accH = __builtin_amdgcn_mfma_f32_16x16x32_bf16(A0[1], B0, accH, 0, 0, 0);
            accL = __builtin_amdgcn_mfma_f32_16x16x32_bf16(A1[0], B1, accL, 0, 0, 0);
            accH = __builtin_amdgcn_mfma_f32_16x16x32_bf16(A1[1], B1, accH, 0, 0, 0);
            #pragma unroll
            for (int r = 0; r < 4; ++r) {
                const float pfL = fbits((bits(accL[r]) & 0xFFFFFC00u)
                                      | (idxv & 0x3FFu));
                m2[0][r] = __builtin_amdgcn_fmed3f(pfL, m1[0][r], m2[0][r]);
                m1[0][r] = fmaxf(pfL, m1[0][r]);
                const float pfH = fbits((bits(accH[r]) & 0xFFFFFC00u)
                                      | (idxv & 0x3FFu));
                m2[1][r] = __builtin_amdgcn_fmed3f(pfH, m1[1][r], m2[1][r]);
                m1[1][r] = fmaxf(pfH, m1[1][r]);
            }
            idxv -= 16u;
        }
        // write tile kt+1 (loaded 2 iterations ago), refill with tile kt+3
        if (kt + 1 < NKT) {
            char* base = &U.p2.a.cbuf[(kt + 1) & 1][srow * 128];
            if ((kt + 1) & 1) {
                *(uint4*)(base + ((sq * 32)      ^ xw)) = rb0;
                *(uint4*)(base + ((sq * 32 + 16) ^ xw)) = rb1;
                if (kt + 3 < NKT) {
                    const uint4* gp = (const uint4*)(wscb
                        + (size_t)(kt + 3) * (KT * 128)
                        + (size_t)srow * 128 + sq * 32);
                    rb0 = gp[0]; rb1 = gp[1];
                }
            } else {
                *(uint4*)(base + ((sq * 32)      ^ xw)) = ra0;
                *(uint4*)(base + ((sq * 32 + 16) ^ xw)) = ra1;
                if (kt + 3 < NKT) {
                    const uint4* gp = (const uint4*)(wscb
                        + (size_t)(kt + 3) * (KT * 128)
                        + (size_t)srow * 128 + sq * 32);
                    ra0 = gp[0]; ra1 = gp[1];
                }
            }
        }
        __syncthreads();
    }
    // cbuf dead from here -> candT may alias it.

    // ---- per-lane top-2 -> candT; C row t = p*64 + wid*16 + lgrp*4 + r ----
    #pragma unroll
    for (int p = 0; p < 2; ++p)
        #pragma unroll
        for (int r = 0; r < 4; ++r) {
            const int trow = p * 64 + (wid << 4) + (lgrp << 2) + r;
            U.p2.a.candT[lrow][trow][0] = bits(m1[p][r]);
            U.p2.a.candT[lrow][trow][1] = bits(m2[p][r]);
        }
    __syncthreads();                                  // S4: candT ready

    // ---- merge top-8 per t (2 threads/t redundantly) ----
    float se0, se1, se2, se3;
    {
        const int t  = tid & 127;
        const int j2 = tid >> 7;       // 0: rescore c1..c4, 1: c5..c8
        float c1 = -INFINITY, c2 = -INFINITY, c3 = -INFINITY, c4 = -INFINITY;
        float c5 = -INFINITY, c6 = -INFINITY, c7 = -INFINITY, c8 = -INFINITY;
        for (int i = 0; i < 16; ++i) {
            const uint2 pv2 = *(const uint2*)&U.p2.a.candT[i][t][0];
            #pragma unroll
            for (int jj = 0; jj < 2; ++jj) {
                const float p = fbits(jj ? pv2.y : pv2.x);
                c8 = fmaxf(fminf(p, c7), c8);
                c7 = fmaxf(fminf(p, c6), c7);
                c6 = fmaxf(fminf(p, c5), c6);
                c5 = fmaxf(fminf(p, c4), c5);
                c4 = fmaxf(fminf(p, c3), c4);
                c3 = fmaxf(fminf(p, c2), c3);
                c2 = fmaxf(fminf(p, c1), c2);
                c1 = fmaxf(p, c1);
            }
        }
        se0 = j2 ? c5 : c1;  se1 = j2 ? c6 : c2;
        se2 = j2 ? c7 : c3;  se3 = j2 ? c8 : c4;
    }
    __syncthreads();                                  // S4b: candT reads done

    // ---- exact fp32 rescore: 4 candidates per thread ----
    {
        const int t  = tid & 127;
        const int j2 = tid >> 7;
        const float* pr  = &U.p2.PL[t * PPAD];
        const float* cbc = cb + (size_t)c * KCB * DDIM;
        const float sels[4] = { se0, se1, se2, se3 };
        #pragma unroll
        for (int e = 0; e < 4; ++e) {
            const int kj = 1023 - (int)(bits(sels[e]) & 0x3FFu);
            const float* cbr = cbc + (size_t)kj * DDIM;
            float a0 = 0.f, a1 = 0.f, a2 = 0.f, a3 = 0.f;
            #pragma unroll
            for (int i = 0; i < 16; ++i) {
                float4 pv = *(const float4*)(pr + i * 4);
                float4 cv = *(const float4*)(cbr + i * 4);
                a0 = fmaf(pv.x, cv.x, a0); a1 = fmaf(pv.y, cv.y, a1);
                a2 = fmaf(pv.z, cv.z, a2); a3 = fmaf(pv.w, cv.w, a3);
            }
            U.p2.a.m.scv[t][4*j2 + e] = ((a0 + a1) + (a2 + a3)) * invn_g[kj];
            U.p2.a.m.sck[t][4*j2 + e] = kj;
        }
    }
    __syncthreads();                                  // S5

    if (tid < TM) {
        const int tg = t0 + tid;
        if (tg < TSTEPS) {
            float best = U.p2.a.m.scv[tid][0];
            int   bk   = U.p2.a.m.sck[tid][0];
            #pragma unroll
            for (int s2 = 1; s2 < 8; ++s2) {
                const float v = U.p2.a.m.scv[tid][s2];
                const int  kk = U.p2.a.m.sck[tid][s2];
                if (v > best || (v == best && kk < bk)) { best = v; bk = kk; }
            }
            out[((size_t)c * B + b) * TSTEPS + tg] = bk;
        }
    }
}

// ------------------------------------------------------------- fallback ----
__global__ __launch_bounds__(TPB, 2) void rpq_fallback(
    const float* __restrict__ mel, const float* __restrict__ proj,
    const float* __restrict__ cb, int* __restrict__ out)
{
    const int tid = threadIdx.x;
    const int b = blockIdx.y, c = blockIdx.z;
    const int t0 = blockIdx.x * (TPB * 2) + tid;
    const int t1 = t0 + TPB;
    const int tc0 = (t0 < TSTEPS) ? t0 : (TSTEPS - 1);
    const int tc1 = (t1 < TSTEPS) ? t1 : (TSTEPS - 1);

    __shared__ union { float projS[NMELS*DDIM]; float cbS[2][64*DDIM]; } sh;
    __shared__ float invn[KCB];
    const float* cbc = cb + (size_t)c * KCB * DDIM;
    {
        const float4* src = (const float4*)(proj + (size_t)c * NMELS * DDIM);
        float4* dst = (float4*)sh.projS;
        for (int i = tid; i < NMELS*DDIM/4; i += TPB) dst[i] = src[i];
    }
    for (int j = 0; j < KCB/TPB; ++j) {
        const int k = j*TPB + tid;
        const float4* r = (const float4*)(cbc + (size_t)k * DDIM);
        float s = 0.f;
        #pragma unroll
        for (int i = 0; i < DDIM/4; ++i) {
            float4 v = r[i]; s += v.x*v.x + v.y*v.y + v.z*v.z + v.w*v.w;
        }
        invn[k] = 1.0f / fmaxf(sqrtf(s), 1e-12f);
    }
    float4 r0, r1, r2, r3;
    { const float4* g = (const float4*)cbc;
      r0 = g[tid]; r1 = g[tid+256]; r2 = g[tid+512]; r3 = g[tid+768]; }
    __syncthreads();
    float P0[DDIM], P1[DDIM];
    #pragma unroll
    for (int d = 0; d < DDIM; ++d) { P0[d] = 0.f; P1[d] = 0.f; }
    const float* mp = mel + (size_t)b * NMELS * TSTEPS;
    for (int n = 0; n < NMELS; ++n) {
        const float m0 = mp[(size_t)n*TSTEPS + tc0];
        const float m1_ = mp[(size_t)n*TSTEPS + tc1];
        const float4* ps = (const float4*)(sh.projS + n*DDIM);
        #pragma unroll
        for (int i = 0; i < DDIM/4; ++i) {
            float4 v = ps[i];
            P0[4*i+0]=fmaf(m0,v.x,P0[4*i+0]); P0[4*i+1]=fmaf(m0,v.y,P0[4*i+1]);
            P0[4*i+2]=fmaf(m0,v.z,P0[4*i+2]); P0[4*i+3]=fmaf(m0,v.w,P0[4*i+3]);
            P1[4*i+0]=fmaf(m1_,v.x,P1[4*i+0]); P1[4*i+1]=fmaf(m1_,v.y,P1[4*i+1]);
            P1[4*i+2]=fmaf(m1_,v.z,P1[4*i+2]); P1[4*i+3]=fmaf(m1_,v.w,P1[4*i+3]);
        }
    }
    __syncthreads();
    { float4* dst = (float4*)sh.cbS[0];
      dst[tid]=r0; dst[tid+256]=r1; dst[tid+512]=r2; dst[tid+768]=r3; }
    { const float4* g = (const float4*)(cbc + (size_t)64*DDIM);
      r0=g[tid]; r1=g[tid+256]; r2=g[tid+512]; r3=g[tid+768]; }
    __syncthreads();
    float best0 = -INFINITY, best1 = -INFINITY; int bi0 = 0, bi1 = 0;
    for (int kt = 0; kt < KCB/64; ++kt) {
        const int cur = kt & 1;
        const float* base = sh.cbS[cur];
        const int kbase = kt * 64;
        #pragma unroll 2
        for (int kk = 0; kk < 64; ++kk) {
            const float4* row = (const float4*)(base + kk*DDIM);
            float a0=0,a1=0,a2=0,a3=0,b0=0,b1=0,b2=0,b3=0;
            #pragma unroll
            for (int i = 0; i < DDIM/4; ++i) {
                float4 v = row[i];
                a0=fmaf(P0[4*i+0],v.x,a0); a1=fmaf(P0[4*i+1],v.y,a1);
                a2=fmaf(P0[4*i+2],v.z,a2); a3=fmaf(P0[4*i+3],v.w,a3);
                b0=fmaf(P1[4*i+0],v.x,b0); b1=fmaf(P1[4*i+1],v.y,b1);
                b2=fmaf(P1[4*i+2],v.z,b2); b3=fmaf(P1[4*i+3],v.w,b3);
            }
            const int k = kbase + kk;
            const float w = invn[k];
            const float s0 = ((a0+a1)+(a2+a3))*w;
            const float s1 = ((b0+b1)+(b2+b3))*w;
            if (s0 > best0) { best0 = s0; bi0 = k; }
            if (s1 > best1) { best1 = s1; bi1 = k; }
        }
        if (kt + 1 < KCB/64) {
            float4* dst = (float4*)sh.cbS[cur ^ 1];
            dst[tid]=r0; dst[tid+256]=r1; dst[tid+512]=r2; dst[tid+768]=r3;
            if (kt + 2 < KCB/64) {
                const float4* g = (const float4*)(cbc + (size_t)(kt+2)*64*DDIM);
                r0=g[tid]; r1=g[tid+256]; r2=g[tid+512]; r3=g[tid+768];
            }
        }
        __syncthreads();
    }
    const size_t ob = ((size_t)c * B + b) * TSTEPS;
    if (t0 < TSTEPS) out[ob + t0] = bi0;
    if (t1 < TSTEPS) out[ob + t1] = bi1;
}

// --------------------------------------------------------------- launch ----
extern "C" void kernel_launch(void* const* d_in, const int* in_sizes, int n_in,
                              void* d_out, int out_size, void* d_ws, size_t ws_size,
                              hipStream_t stream) {
    const float* mel  = (const float*)d_in[0];
    const float* proj = (const float*)d_in[1];
    const float* cb   = (const float*)d_in[2];
    int* out = (int*)d_out;

    if (ws_size >= (size_t)WS_NEEDED) {   // proven true on this harness (R4)
        float* ws = (float*)d_ws;
        rpq_prep<<<dim3((NCB*KCB + TPB - 1)/TPB), dim3(TPB), 0, stream>>>(cb, ws);
        dim3 grid((TSTEPS + TM - 1) / TM, B, NCB);     // (32, 32, 2) = 2048
        rpq_main<<<grid, dim3(TPB), 0, stream>>>(mel, proj, cb, ws, out);
    } else {
        dim3 grid((TSTEPS + TPB*2 - 1) / (TPB*2), B, NCB);
        rpq_fallback<<<grid, dim3(TPB), 0, stream>>>(mel, proj, cb, out);
    }
}

// Round 15
// 157.936 us; speedup vs baseline: 1.2098x; 1.0829x over previous
//
#include <hip/hip_runtime.h>
#include <hip/hip_bf16.h>
#include <math.h>
#include <stdint.h>

// RandomProjectionQuantizer — bf16 MFMA filter + exact fp32 top-8 rescore.
//   mel [32,80,4000] f32, proj [2,80,64] f32, codebooks [2,1024,64] f32
//   codes[c,b,t] = argmax_k ( (mel[b,:,t] @ proj[c]) . cb[c,k,:]/||cb[c,k]|| )
//
// R15 = R11 (169us) + melS LDS staging for phase-1 + launch_bounds(256,3):
//   - mel tile (80n x 64t = 20KB) staged coalesced before S1; phase-1 reads
//     become ds_read_b128 (no 80-deep global-load chain, no 16x L1 redundancy
//     from the (tq,dg) remap). The one remaining long-latency per-wave chain.
//   - union p1{projS,melS}=40960B over p2{cbuf,PL,cand,scv,sck}=33280B; all
//     p2 writes post-S2 (audited). LDS 40960 = exactly 4 blocks/CU.
//   - arg=3 -> VGPR cap 85 (empirical cap=512/(2*arg)); R11's arg=4 capped at
//     64 and squeezed the scheduler (VGPR_Count sat at 64).
// Filter/staging/swizzle/MFMA-mapping/top-2/top-8/rescore: proven lineage.

#define B      32
#define NMELS  80
#define TSTEPS 4000
#define NCB    2
#define KCB    1024
#define DDIM   64
#define TPB    256
#define TM     64            // t's per block (16 per wave)
#define KT     64            // codebook rows per LDS tile (8 KB bf16)
#define NKT    (KCB / KT)    // 16 tiles
#define PPAD   66            // P row stride (floats) — proven

typedef short bf16x8 __attribute__((ext_vector_type(8)));
typedef float f32x4  __attribute__((ext_vector_type(4)));

#define WS_CB_OFF   8192                         // bytes: invn table first
#define WS_NEEDED   (8192 + NCB*KCB*DDIM*2)      // 270336 (proven fits, R4)

static __device__ __forceinline__ uint32_t bits(float f) {
    return __builtin_bit_cast(uint32_t, f);
}
static __device__ __forceinline__ float fbits(uint32_t u) {
    return __builtin_bit_cast(float, u);
}
// round-to-nearest-even f32 -> bf16 (returns low 16 bits)
static __device__ __forceinline__ uint32_t rne16(uint32_t u) {
    return (u + 0x7FFFu + ((u >> 16) & 1u)) >> 16;
}

// ---------------------------------------------------------------- prep ----
__global__ __launch_bounds__(TPB) void rpq_prep(const float* __restrict__ cb,
                                                float* __restrict__ ws)
{
    const int idx = blockIdx.x * TPB + threadIdx.x;
    if (idx >= NCB * KCB) return;

    const float4* row = (const float4*)(cb + (size_t)idx * DDIM);
    float4 v[16];
    float ss = 0.f;
    #pragma unroll
    for (int i = 0; i < 16; ++i) {
        v[i] = row[i];
        ss += v[i].x*v[i].x + v[i].y*v[i].y + v[i].z*v[i].z + v[i].w*v[i].w;
    }
    const float inv = 1.0f / fmaxf(sqrtf(ss), 1e-12f);
    ws[idx] = inv;

    uint32_t dw[32];
    #pragma unroll
    for (int i = 0; i < 16; ++i) {
        dw[2*i]   = rne16(bits(v[i].x * inv)) | (rne16(bits(v[i].y * inv)) << 16);
        dw[2*i+1] = rne16(bits(v[i].z * inv)) | (rne16(bits(v[i].w * inv)) << 16);
    }
    uint4* dst = (uint4*)((char*)ws + WS_CB_OFF + (size_t)idx * 128);
    #pragma unroll
    for (int i = 0; i < 8; ++i)
        dst[i] = make_uint4(dw[4*i], dw[4*i+1], dw[4*i+2], dw[4*i+3]);
}

// ---------------------------------------------------------------- main ----
__global__ __launch_bounds__(TPB, 3) void rpq_main(
    const float* __restrict__ mel,
    const float* __restrict__ proj,
    const float* __restrict__ cb,
    const float* __restrict__ ws,
    int* __restrict__ out)
{
    const int tid  = threadIdx.x;
    const int b    = blockIdx.y;
    const int c    = blockIdx.z;
    const int t0   = blockIdx.x * TM;

    const int l    = tid & 63;
    const int wid  = tid >> 6;      // wave 0..3
    const int lrow = l & 15;        // A/B row-col within 16x16
    const int lgrp = l >> 4;        // k-octet group 0..3

    // p1 (projS+melS): phase-1 only, dead after S2. p2 written after S2:
    // cbuf (bytes 0..16383) and PL (16384..33279) overlay p1; cand/scv/sck
    // overlay cbuf after the filter's final barrier.
    __shared__ union __align__(16) {
        struct {
            float projS[NMELS * DDIM];          // 20480 B
            float melS[NMELS * TM];             // 20480 B  [n][t] t-fastest
        } p1;                                   // 40960 B
        struct {
            union {
                char cbuf[2][KT * 128];         // 16384 B (bf16 dbuf, swizzled)
                struct {
                    uint32_t cand[TM][17][2];   // 8704 B
                    float    scv[TM][8];        // 2048 B
                    int      sck[TM][8];        // 2048 B
                } m;
            } a;
            float PL[TM * PPAD];                // 16896 B
        } p2;                                   // 33280 B
    } U;                                        // 40960 B -> 4 blocks/CU

    const char*  wscb   = (const char*)ws + WS_CB_OFF + (size_t)c * (KCB * 128);
    const float* invn_g = ws + (size_t)c * KCB;

    // ---- stage proj[c] + mel tile into LDS (both coalesced) ----
    {
        const float4* src = (const float4*)(proj + (size_t)c * NMELS * DDIM);
        float4* dst = (float4*)U.p1.projS;
        for (int i = tid; i < NMELS * DDIM / 4; i += TPB) dst[i] = src[i];

        const size_t mbase = (size_t)b * NMELS * TSTEPS;
        #pragma unroll
        for (int it = 0; it < 5; ++it) {        // 1280 float4 / 256 thr
            const int f    = tid + it * TPB;
            const int row  = f >> 4;            // n
            const int cpos = f & 15;            // float4 slot in 64-t row
            int tg = t0 + cpos * 4;
            if (tg > TSTEPS - 4) tg = TSTEPS - 4;   // last-block clamp
            *(float4*)&U.p1.melS[row * TM + cpos * 4] =
                *(const float4*)(mel + mbase + (size_t)row * TSTEPS + tg);
        }
    }
    __syncthreads();                                  // S1

    // ---- DEPTH-2 prefetch: issue tile-0 AND tile-1 loads before phase-1 ----
    const int srow = tid >> 2;     // staging row 0..63
    const int sq   = tid & 3;      // 32-byte quarter
    uint4 ra0, ra1, rb0, rb1;
    {
        const uint4* gp0 = (const uint4*)(wscb + (size_t)srow * 128 + sq * 32);
        ra0 = gp0[0]; ra1 = gp0[1];                   // tile 0 -> RA
        const uint4* gp1 = (const uint4*)(wscb + (size_t)KT * 128
                                          + (size_t)srow * 128 + sq * 32);
        rb0 = gp1[0]; rb1 = gp1[1];                   // tile 1 -> RB
    }

    // ---- phase 1: P[t][d] from LDS only; thread = (tq -> 4 t's, dg -> 4 d's)
    {
        const int tq = tid & 15;
        const int dg = tid >> 4;

        float Pa[4][4];
        #pragma unroll
        for (int i = 0; i < 4; ++i)
            #pragma unroll
            for (int j = 0; j < 4; ++j) Pa[i][j] = 0.f;

        for (int n = 0; n < NMELS; ++n) {
            const float4 m4 = *(const float4*)&U.p1.melS[n * TM + tq * 4];
            const float4 w  = *(const float4*)&U.p1.projS[n * DDIM + dg * 4];
            Pa[0][0] = fmaf(m4.x, w.x, Pa[0][0]); Pa[0][1] = fmaf(m4.x, w.y, Pa[0][1]);
            Pa[0][2] = fmaf(m4.x, w.z, Pa[0][2]); Pa[0][3] = fmaf(m4.x, w.w, Pa[0][3]);
            Pa[1][0] = fmaf(m4.y, w.x, Pa[1][0]); Pa[1][1] = fmaf(m4.y, w.y, Pa[1][1]);
            Pa[1][2] = fmaf(m4.y, w.z, Pa[1][2]); Pa[1][3] = fmaf(m4.y, w.w, Pa[1][3]);
            Pa[2][0] = fmaf(m4.z, w.x, Pa[2][0]); Pa[2][1] = fmaf(m4.z, w.y, Pa[2][1]);
            Pa[2][2] = fmaf(m4.z, w.z, Pa[2][2]); Pa[2][3] = fmaf(m4.z, w.w, Pa[2][3]);
            Pa[3][0] = fmaf(m4.w, w.x, Pa[3][0]); Pa[3][1] = fmaf(m4.w, w.y, Pa[3][1]);
            Pa[3][2] = fmaf(m4.w, w.z, Pa[3][2]); Pa[3][3] = fmaf(m4.w, w.w, Pa[3][3]);
        }
        __syncthreads();                              // S2: p1 reads done

        #pragma unroll
        for (int i = 0; i < 4; ++i)
            *(float4*)&U.p2.PL[(tq * 4 + i) * PPAD + dg * 4] =
                make_float4(Pa[i][0], Pa[i][1], Pa[i][2], Pa[i][3]);
    }

    // ---- write tile 0 from RA; refill RA with tile 2 ----
    const int xw = (srow & 7) << 4;
    {
        char* base = &U.p2.a.cbuf[0][srow * 128];
        *(uint4*)(base + ((sq * 32)      ^ xw)) = ra0;
        *(uint4*)(base + ((sq * 32 + 16) ^ xw)) = ra1;
        const uint4* gp = (const uint4*)(wscb + (size_t)2 * (KT * 128)
                                         + (size_t)srow * 128 + sq * 32);
        ra0 = gp[0]; ra1 = gp[1];                     // tile 2 -> RA
    }
    __syncthreads();                                  // S3: PL + tile0 ready

    // ---- A fragments (bf16 RNE) from PL ----
    bf16x8 A0, A1;
    {
        const float* pr = &U.p2.PL[((wid << 4) + lrow) * PPAD];
        #pragma unroll
        for (int i = 0; i < 8; ++i) {
            A0[i] = (short)rne16(bits(pr[lgrp * 8 + i]));        // d 0..31
            A1[i] = (short)rne16(bits(pr[32 + lgrp * 8 + i]));   // d 32..63
        }
    }

    // ---- filter loop over 16 tiles, depth-2 pipelined staging ----
    float m1[4], m2[4];
    #pragma unroll
    for (int r = 0; r < 4; ++r) { m1[r] = -INFINITY; m2[r] = -INFINITY; }
    uint32_t idxv = (uint32_t)(1023 - lrow);  // payload = 1023 - k

    const int xr  = (lrow & 7) << 4;
    const int bo0 = (lgrp * 16) ^ xr;
    const int bo1 = (64 + lgrp * 16) ^ xr;

    #pragma unroll 2
    for (int kt = 0; kt < NKT; ++kt) {
        const char* buf = U.p2.a.cbuf[kt & 1];
        #pragma unroll
        for (int s = 0; s < 4; ++s) {
            const char* rowp = buf + (s * 16 + lrow) * 128;
            bf16x8 B0 = *(const bf16x8*)(rowp + bo0);
            bf16x8 B1 = *(const bf16x8*)(rowp + bo1);
            f32x4 acc = {0.f, 0.f, 0.f, 0.f};
            acc = __builtin_amdgcn_mfma_f32_16x16x32_bf16(A0, B0, acc, 0, 0, 0);
            acc = __builtin_amdgcn_mfma_f32_16x16x32_bf16(A1, B1, acc, 0, 0, 0);
            #pragma unroll
            for (int r = 0; r < 4; ++r) {
                const float pf = fbits((bits(acc[r]) & 0xFFFFFC00u)
                                     | (idxv & 0x3FFu));
                m2[r] = __builtin_amdgcn_fmed3f(pf, m1[r], m2[r]);
                m1[r] = fmaxf(pf, m1[r]);
            }
            idxv -= 16u;
        }
        // write tile kt+1 (loaded 2 iterations ago -> vmcnt satisfied),
        // then refill that reg set with tile kt+3.
        if (kt + 1 < NKT) {
            char* base = &U.p2.a.cbuf[(kt + 1) & 1][srow * 128];
            if ((kt + 1) & 1) {
                *(uint4*)(base + ((sq * 32)      ^ xw)) = rb0;
                *(uint4*)(base + ((sq * 32 + 16) ^ xw)) = rb1;
                if (kt + 3 < NKT) {
                    const uint4* gp = (const uint4*)(wscb
                        + (size_t)(kt + 3) * (KT * 128)
                        + (size_t)srow * 128 + sq * 32);
                    rb0 = gp[0]; rb1 = gp[1];
                }
            } else {
                *(uint4*)(base + ((sq * 32)      ^ xw)) = ra0;
                *(uint4*)(base + ((sq * 32 + 16) ^ xw)) = ra1;
                if (kt + 3 < NKT) {
                    const uint4* gp = (const uint4*)(wscb
                        + (size_t)(kt + 3) * (KT * 128)
                        + (size_t)srow * 128 + sq * 32);
                    ra0 = gp[0]; ra1 = gp[1];
                }
            }
        }
        __syncthreads();
    }
    // cbuf is dead from here -> cand may alias it.

    // ---- per-lane top-2 -> cand; C row t = wid*16 + lgrp*4 + r (m89) ----
    #pragma unroll
    for (int r = 0; r < 4; ++r) {
        const int trow = (wid << 4) + (lgrp << 2) + r;
        U.p2.a.m.cand[trow][lrow][0] = bits(m1[r]);
        U.p2.a.m.cand[trow][lrow][1] = bits(m2[r]);
    }
    __syncthreads();                                  // S4

    // ---- merge top-8 per t (4 threads/t redundantly), rescore 2 each ----
    {
        const int t = tid & 63;
        const int j = wid;
        float c1 = -INFINITY, c2 = -INFINITY, c3 = -INFINITY, c4 = -INFINITY;
        float c5 = -INFINITY, c6 = -INFINITY, c7 = -INFINITY, c8 = -INFINITY;
        for (int i = 0; i < 16; ++i) {
            #pragma unroll
            for (int jj = 0; jj < 2; ++jj) {
                const float p = fbits(U.p2.a.m.cand[t][i][jj]);
                c8 = fmaxf(fminf(p, c7), c8);
                c7 = fmaxf(fminf(p, c6), c7);
                c6 = fmaxf(fminf(p, c5), c6);
                c5 = fmaxf(fminf(p, c4), c5);
                c4 = fmaxf(fminf(p, c3), c4);
                c3 = fmaxf(fminf(p, c2), c3);
                c2 = fmaxf(fminf(p, c1), c2);
                c1 = fmaxf(p, c1);
            }
        }
        const float sel0 = (j == 0) ? c1 : (j == 1) ? c3 : (j == 2) ? c5 : c7;
        const float sel1 = (j == 0) ? c2 : (j == 1) ? c4 : (j == 2) ? c6 : c8;
        const float* pr  = &U.p2.PL[t * PPAD];
        const float* cbc = cb + (size_t)c * KCB * DDIM;
        #pragma unroll
        for (int e = 0; e < 2; ++e) {
            const float sel = e ? sel1 : sel0;
            const int kj = 1023 - (int)(bits(sel) & 0x3FFu);
            const float* cbr = cbc + (size_t)kj * DDIM;
            float a0 = 0.f, a1 = 0.f, a2 = 0.f, a3 = 0.f;
            #pragma unroll
            for (int i = 0; i < 16; ++i) {
                float4 pv = *(const float4*)(pr + i * 4);
                float4 cv = *(const float4*)(cbr + i * 4);
                a0 = fmaf(pv.x, cv.x, a0); a1 = fmaf(pv.y, cv.y, a1);
                a2 = fmaf(pv.z, cv.z, a2); a3 = fmaf(pv.w, cv.w, a3);
            }
            U.p2.a.m.scv[t][2*j + e] = ((a0 + a1) + (a2 + a3)) * invn_g[kj];
            U.p2.a.m.sck[t][2*j + e] = kj;
        }
    }
    __syncthreads();                                  // S5

    if (tid < TM) {
        const int tg = t0 + tid;
        if (tg < TSTEPS) {
            float best = U.p2.a.m.scv[tid][0];
            int   bk   = U.p2.a.m.sck[tid][0];
            #pragma unroll
            for (int s2 = 1; s2 < 8; ++s2) {
                const float v = U.p2.a.m.scv[tid][s2];
                const int  kk = U.p2.a.m.sck[tid][s2];
                if (v > best || (v == best && kk < bk)) { best = v; bk = kk; }
            }
            out[((size_t)c * B + b) * TSTEPS + tg] = bk;
        }
    }
}

// ------------------------------------------------------------- fallback ----
__global__ __launch_bounds__(TPB, 2) void rpq_fallback(
    const float* __restrict__ mel, const float* __restrict__ proj,
    const float* __restrict__ cb, int* __restrict__ out)
{
    const int tid = threadIdx.x;
    const int b = blockIdx.y, c = blockIdx.z;
    const int t0 = blockIdx.x * (TPB * 2) + tid;
    const int t1 = t0 + TPB;
    const int tc0 = (t0 < TSTEPS) ? t0 : (TSTEPS - 1);
    const int tc1 = (t1 < TSTEPS) ? t1 : (TSTEPS - 1);

    __shared__ union { float projS[NMELS*DDIM]; float cbS[2][64*DDIM]; } sh;
    __shared__ float invn[KCB];
    const float* cbc = cb + (size_t)c * KCB * DDIM;
    {
        const float4* src = (const float4*)(proj + (size_t)c * NMELS * DDIM);
        float4* dst = (float4*)sh.projS;
        for (int i = tid; i < NMELS*DDIM/4; i += TPB) dst[i] = src[i];
    }
    for (int j = 0; j < KCB/TPB; ++j) {
        const int k = j*TPB + tid;
        const float4* r = (const float4*)(cbc + (size_t)k * DDIM);
        float s = 0.f;
        #pragma unroll
        for (int i = 0; i < DDIM/4; ++i) {
            float4 v = r[i]; s += v.x*v.x + v.y*v.y + v.z*v.z + v.w*v.w;
        }
        invn[k] = 1.0f / fmaxf(sqrtf(s), 1e-12f);
    }
    float4 r0, r1, r2, r3;
    { const float4* g = (const float4*)cbc;
      r0 = g[tid]; r1 = g[tid+256]; r2 = g[tid+512]; r3 = g[tid+768]; }
    __syncthreads();
    float P0[DDIM], P1[DDIM];
    #pragma unroll
    for (int d = 0; d < DDIM; ++d) { P0[d] = 0.f; P1[d] = 0.f; }
    const float* mp = mel + (size_t)b * NMELS * TSTEPS;
    for (int n = 0; n < NMELS; ++n) {
        const float m0 = mp[(size_t)n*TSTEPS + tc0];
        const float m1_ = mp[(size_t)n*TSTEPS + tc1];
        const float4* ps = (const float4*)(sh.projS + n*DDIM);
        #pragma unroll
        for (int i = 0; i < DDIM/4; ++i) {
            float4 v = ps[i];
            P0[4*i+0]=fmaf(m0,v.x,P0[4*i+0]); P0[4*i+1]=fmaf(m0,v.y,P0[4*i+1]);
            P0[4*i+2]=fmaf(m0,v.z,P0[4*i+2]); P0[4*i+3]=fmaf(m0,v.w,P0[4*i+3]);
            P1[4*i+0]=fmaf(m1_,v.x,P1[4*i+0]); P1[4*i+1]=fmaf(m1_,v.y,P1[4*i+1]);
            P1[4*i+2]=fmaf(m1_,v.z,P1[4*i+2]); P1[4*i+3]=fmaf(m1_,v.w,P1[4*i+3]);
        }
    }
    __syncthreads();
    { float4* dst = (float4*)sh.cbS[0];
      dst[tid]=r0; dst[tid+256]=r1; dst[tid+512]=r2; dst[tid+768]=r3; }
    { const float4* g = (const float4*)(cbc + (size_t)64*DDIM);
      r0=g[tid]; r1=g[tid+256]; r2=g[tid+512]; r3=g[tid+768]; }
    __syncthreads();
    float best0 = -INFINITY, best1 = -INFINITY; int bi0 = 0, bi1 = 0;
    for (int kt = 0; kt < KCB/64; ++kt) {
        const int cur = kt & 1;
        const float* base = sh.cbS[cur];
        const int kbase = kt * 64;
        #pragma unroll 2
        for (int kk = 0; kk < 64; ++kk) {
            const float4* row = (const float4*)(base + kk*DDIM);
            float a0=0,a1=0,a2=0,a3=0,b0=0,b1=0,b2=0,b3=0;
            #pragma unroll
            for (int i = 0; i < DDIM/4; ++i) {
                float4 v = row[i];
                a0=fmaf(P0[4*i+0],v.x,a0); a1=fmaf(P0[4*i+1],v.y,a1);
                a2=fmaf(P0[4*i+2],v.z,a2); a3=fmaf(P0[4*i+3],v.w,a3);
                b0=fmaf(P1[4*i+0],v.x,b0); b1=fmaf(P1[4*i+1],v.y,b1);
                b2=fmaf(P1[4*i+2],v.z,b2); b3=fmaf(P1[4*i+3],v.w,b3);
            }
            const int k = kbase + kk;
            const float w = invn[k];
            const float s0 = ((a0+a1)+(a2+a3))*w;
            const float s1 = ((b0+b1)+(b2+b3))*w;
            if (s0 > best0) { best0 = s0; bi0 = k; }
            if (s1 > best1) { best1 = s1; bi1 = k; }
        }
        if (kt + 1 < KCB/64) {
            float4* dst = (float4*)sh.cbS[cur ^ 1];
            dst[tid]=r0; dst[tid+256]=r1; dst[tid+512]=r2; dst[tid+768]=r3;
            if (kt + 2 < KCB/64) {
                const float4* g = (const float4*)(cbc + (size_t)(kt+2)*64*DDIM);
                r0=g[tid]; r1=g[tid+256]; r2=g[tid+512]; r3=g[tid+768];
            }
        }
        __syncthreads();
    }
    const size_t ob = ((size_t)c * B + b) * TSTEPS;
    if (t0 < TSTEPS) out[ob + t0] = bi0;
    if (t1 < TSTEPS) out[ob + t1] = bi1;
}

// --------------------------------------------------------------- launch ----
extern "C" void kernel_launch(void* const* d_in, const int* in_sizes, int n_in,
                              void* d_out, int out_size, void* d_ws, size_t ws_size,
                              hipStream_t stream) {
    const float* mel  = (const float*)d_in[0];
    const float* proj = (const float*)d_in[1];
    const float* cb   = (const float*)d_in[2];
    int* out = (int*)d_out;

    if (ws_size >= (size_t)WS_NEEDED) {   // proven true on this harness (R4)
        float* ws = (float*)d_ws;
        rpq_prep<<<dim3((NCB*KCB + TPB - 1)/TPB), dim3(TPB), 0, stream>>>(cb, ws);
        dim3 grid((TSTEPS + TM - 1) / TM, B, NCB);     // (63, 32, 2)
        rpq_main<<<grid, dim3(TPB), 0, stream>>>(mel, proj, cb, ws, out);
    } else {
        dim3 grid((TSTEPS + TPB*2 - 1) / (TPB*2), B, NCB);
        rpq_fallback<<<grid, dim3(TPB), 0, stream>>>(mel, proj, cb, out);
    }
}